// Round 11
// baseline (2289.935 us; speedup 1.0000x reference)
//
#include <hip/hip_runtime.h>
#include <hip/hip_bf16.h>

// DigitCaps dynamic routing. Output fp32.
// R11: fused coop kernel, tree barrier; fixes R10's two defects:
//  (1) coop launch attempted UNCONDITIONALLY (R9 proved this captures; R10's
//      occupancy gate silently diverted to fallback — fused never ran).
//  (2) B-build back to its own tiny global-Bs phase (R8-proven ~2us) +
//      R9's proven sgemm unit; R10's fused-in-LDS build was ~8x redundant.
// 12 gsyncs x ~4us (tree: 32 leaves->root->gen, agent scope, device globals
// untouched by 0xAA ws poison) + ~80us phase work -> predict ~120-160us.
#define B 512
#define IC 1152
#define QD 8
#define OD 10
#define PD 16
#define KD (IC * QD)       // 9216
#define NKB (KD / 32)      // 288 K32 blocks
#define NCS 36             // K-chunks for s GEMM; 288/36 = 8 K-steps
#define KSTEPS (NKB / NCS)
#define NCB 16             // b-chunks for agreement
#define CSB (B / NCB)      // 32
#define SOP (B * OD * PD)  // 81920
#define SUNITS 576         // sgemm units (16 mn x 36 cz) == agree units (144 ig x 4 bq)

typedef short bf16x8 __attribute__((ext_vector_type(8)));
typedef float f32x4 __attribute__((ext_vector_type(4)));

__device__ __forceinline__ short f2bf(float f) {
  union { float f; unsigned u; } x;
  x.f = f;
  unsigned r = x.u + 0x7FFFu + ((x.u >> 16) & 1u);  // RNE to bf16
  return (short)(r >> 16);
}

// ---------------- tree barrier (device-global state, self-resetting) --------
__device__ int g_leaf[32];
__device__ int g_root;
__device__ unsigned g_gen;

__device__ __forceinline__ void gsync(int nblk) {
  __syncthreads();
  if (threadIdx.x == 0) {
    __threadfence();
    const int lid = blockIdx.x & 31;
    const int leafcnt = (nblk >> 5) + ((lid < (nblk & 31)) ? 1 : 0);
    const unsigned g = __hip_atomic_load(&g_gen, __ATOMIC_RELAXED, __HIP_MEMORY_SCOPE_AGENT);
    const int lv = __hip_atomic_fetch_add(&g_leaf[lid], 1, __ATOMIC_ACQ_REL, __HIP_MEMORY_SCOPE_AGENT);
    if (lv == leafcnt - 1) {
      __hip_atomic_store(&g_leaf[lid], 0, __ATOMIC_RELAXED, __HIP_MEMORY_SCOPE_AGENT);
      const int nleaf = (nblk < 32) ? nblk : 32;
      const int rv = __hip_atomic_fetch_add(&g_root, 1, __ATOMIC_ACQ_REL, __HIP_MEMORY_SCOPE_AGENT);
      if (rv == nleaf - 1) {
        __hip_atomic_store(&g_root, 0, __ATOMIC_RELAXED, __HIP_MEMORY_SCOPE_AGENT);
        __hip_atomic_fetch_add(&g_gen, 1u, __ATOMIC_RELEASE, __HIP_MEMORY_SCOPE_AGENT);
      }
    }
    while (__hip_atomic_load(&g_gen, __ATOMIC_ACQUIRE, __HIP_MEMORY_SCOPE_AGENT) == g) {
      __builtin_amdgcn_s_sleep(2);
    }
    __threadfence();
  }
  __syncthreads();
}

// ---------------- phases ----------------------------------------------------

// Bs[kb][n][quad][j] = bf16(c[i,o]*W[i,o,p,q]); c = exp(bij-mx[o])*inv[o].
__device__ __forceinline__ void phase_build_b(const float* __restrict__ W,
                                              const float* __restrict__ bij,
                                              const float* __restrict__ stats,
                                              int uniform, short* __restrict__ Bs,
                                              int gtid, int nthreads) {
  for (int t = gtid; t < NKB * 160; t += nthreads) {
    const int kb = t / 160, n = t % 160;
    const int o = n >> 4, p = n & 15;
    short ov[32];
#pragma unroll
    for (int quad = 0; quad < 4; ++quad) {
      const int i = kb * 4 + quad;
      float ci;
      if (uniform) ci = 1.0f / (float)IC;
      else ci = __expf(bij[i * OD + o] - stats[2 * o]) * stats[2 * o + 1];
      const float4* wp = (const float4*)(W + (((size_t)i * OD + o) * PD + p) * QD);
      const float4 w0 = wp[0], w1 = wp[1];
      ov[quad * 8 + 0] = f2bf(ci * w0.x); ov[quad * 8 + 1] = f2bf(ci * w0.y);
      ov[quad * 8 + 2] = f2bf(ci * w0.z); ov[quad * 8 + 3] = f2bf(ci * w0.w);
      ov[quad * 8 + 4] = f2bf(ci * w1.x); ov[quad * 8 + 5] = f2bf(ci * w1.y);
      ov[quad * 8 + 6] = f2bf(ci * w1.z); ov[quad * 8 + 7] = f2bf(ci * w1.w);
    }
    int4* dst = (int4*)(Bs + (size_t)t * 32);
    const int4* src = (const int4*)ov;
#pragma unroll
    for (int j = 0; j < 4; ++j) dst[j] = src[j];
  }
}

// s_part[cz][b][n] partial GEMM, R9-proven unit. unit: mn=u/NCS, cz=u%NCS.
__device__ __forceinline__ void phase_sgemm_unit(const float* __restrict__ x,
                                                 const short* __restrict__ Bs,
                                                 float* __restrict__ s_part,
                                                 int unit, int wave, int lane) {
  const int cz = unit % NCS;
  const int mn = unit / NCS;  // 0..15
  const int mb = mn >> 1, nh = mn & 1;
  const int ln = lane & 15, quad = lane >> 4;
  const int m0 = mb * 64 + wave * 16;
  const int nb = nh * 80;
  f32x4 acc[5] = {};
  const float* arow = x + (size_t)(m0 + ln) * KD + quad * 8;
#pragma unroll 2
  for (int step = 0; step < KSTEPS; ++step) {
    const int kb = cz * KSTEPS + step;
    const float* ap = arow + kb * 32;
    const f32x4 a0 = *(const f32x4*)ap;
    const f32x4 a1 = *(const f32x4*)(ap + 4);
    bf16x8 af;
    af[0] = f2bf(a0[0]); af[1] = f2bf(a0[1]); af[2] = f2bf(a0[2]); af[3] = f2bf(a0[3]);
    af[4] = f2bf(a1[0]); af[5] = f2bf(a1[1]); af[6] = f2bf(a1[2]); af[7] = f2bf(a1[3]);
    const short* bp = Bs + (size_t)kb * 5120 + (nb + ln) * 32 + quad * 8;
#pragma unroll
    for (int nt = 0; nt < 5; ++nt) {
      const bf16x8 bf = *(const bf16x8*)(bp + nt * 512);
      acc[nt] = __builtin_amdgcn_mfma_f32_16x16x32_bf16(af, bf, acc[nt], 0, 0, 0);
    }
  }
  // C/D layout: col = lane&15, row = quad*4 + reg  [m89-verified]
  float* sp = s_part + (size_t)cz * SOP;
#pragma unroll
  for (int nt = 0; nt < 5; ++nt)
#pragma unroll
    for (int r = 0; r < 4; ++r)
      sp[(size_t)(m0 + quad * 4 + r) * 160 + nb + nt * 16 + ln] = acc[nt][r];
}

__device__ __forceinline__ void phase_squash(const float* __restrict__ s_part,
                                             float* __restrict__ v,
                                             float* __restrict__ out,
                                             int write_out, int gtid, int nthreads) {
  for (int t = gtid; t < SOP; t += nthreads) {
    float sv = 0.f;
#pragma unroll 6
    for (int ch = 0; ch < NCS; ++ch) sv += s_part[(size_t)ch * SOP + t];
    float sq = sv * sv;
#pragma unroll
    for (int m = 1; m < 16; m <<= 1) sq += __shfl_xor(sq, m, 16);
    const float norm = sqrtf(sq + 1e-8f);
    const float val = sv * (sq / ((1.f + sq) * norm));
    v[t] = val;
    if (write_out) out[t] = val;
  }
}

// u_part[bc][i][o]; unit = ig*4 + bquad; block stages x[bq*128..+128)[ig*8..+8)[:]
// in LDS once (32KB); 4 waves = 4 b-chunks of 32; 5 o-pairs reuse the tile.
__device__ __forceinline__ void phase_agree(const float* __restrict__ x,
                                            const float* __restrict__ W,
                                            const float* __restrict__ v,
                                            float* __restrict__ u_part,
                                            float* xs, int blk, int nblk, int tid) {
  const int wave = tid >> 6, lane = tid & 63;
  const int il = lane >> 3, q = lane & 7;
  for (int u0 = blk; u0 < SUNITS; u0 += nblk) {
    const int ig = u0 >> 2, bquad = u0 & 3;
    const int bbase = bquad * 128;
    const int i = ig * 8 + il;
    __syncthreads();
    for (int idx = tid; idx < 2048; idx += 256) {
      const int row = idx >> 4, f4 = idx & 15;
      *(float4*)(xs + row * 64 + f4 * 4) =
          *(const float4*)(x + (size_t)(bbase + row) * KD + ig * 64 + f4 * 4);
    }
    __syncthreads();
    const int bc = bquad * 4 + wave;
    const int b0 = bc * CSB;
    const float* xw = xs + wave * 32 * 64 + il * 8 + q;
#pragma unroll
    for (int opair = 0; opair < 5; ++opair) {
      const int o1 = opair, o2 = opair + 5;
      float G0[PD], G1[PD];
#pragma unroll
      for (int p = 0; p < PD; ++p) { G0[p] = 0.f; G1[p] = 0.f; }
      for (int b = 0; b < CSB; ++b) {
        const float xa = xw[b * 64];
        const int vo0 = __builtin_amdgcn_readfirstlane(((b0 + b) * OD + o1) * PD);
        const int vo1 = __builtin_amdgcn_readfirstlane(((b0 + b) * OD + o2) * PD);
        const float4* vp0 = (const float4*)(v + vo0);
        const float4* vp1 = (const float4*)(v + vo1);
        const float4 a0 = vp0[0], a1 = vp0[1], a2 = vp0[2], a3 = vp0[3];
        const float4 c0 = vp1[0], c1 = vp1[1], c2 = vp1[2], c3 = vp1[3];
        const float va[PD] = {a0.x, a0.y, a0.z, a0.w, a1.x, a1.y, a1.z, a1.w,
                              a2.x, a2.y, a2.z, a2.w, a3.x, a3.y, a3.z, a3.w};
        const float vc[PD] = {c0.x, c0.y, c0.z, c0.w, c1.x, c1.y, c1.z, c1.w,
                              c2.x, c2.y, c2.z, c2.w, c3.x, c3.y, c3.z, c3.w};
#pragma unroll
        for (int p = 0; p < PD; ++p) G0[p] = fmaf(xa, va[p], G0[p]);
#pragma unroll
        for (int p = 0; p < PD; ++p) G1[p] = fmaf(xa, vc[p], G1[p]);
      }
      const float* wq1 = W + ((size_t)(i * OD + o1) * PD) * QD + q;
      const float* wq2 = W + ((size_t)(i * OD + o2) * PD) * QD + q;
      float u0s = 0.f, u1s = 0.f;
#pragma unroll
      for (int p = 0; p < PD; ++p) {
        u0s = fmaf(wq1[(size_t)p * QD], G0[p], u0s);
        u1s = fmaf(wq2[(size_t)p * QD], G1[p], u1s);
      }
      u0s += __shfl_xor(u0s, 1); u0s += __shfl_xor(u0s, 2); u0s += __shfl_xor(u0s, 4);
      u1s += __shfl_xor(u1s, 1); u1s += __shfl_xor(u1s, 2); u1s += __shfl_xor(u1s, 4);
      if (q == 0) {
        float* up = u_part + ((size_t)bc * IC + i) * OD;
        up[o1] = u0s * (1.0f / (float)B);
        up[o2] = u1s * (1.0f / (float)B);
      }
    }
  }
}

// bij += sum_chunk u_part; stats[o] = (max_i bij, 1/sum_i exp(bij-max)).
__device__ __forceinline__ void phase_route(const float* __restrict__ u_part,
                                            float* __restrict__ bij,
                                            float* __restrict__ stats,
                                            int add_prev, float* red, int blk, int nblk, int tid) {
  for (int o = blk; o < OD; o += nblk) {
    __syncthreads();
    float val[5];
    float lmax = -1e30f;
#pragma unroll
    for (int k = 0; k < 5; ++k) {
      const int i = tid + k * 256;
      if (i < IC) {
        float sacc = add_prev ? bij[i * OD + o] : 0.f;
#pragma unroll
        for (int ch = 0; ch < NCB; ++ch) sacc += u_part[((size_t)ch * IC + i) * OD + o];
        val[k] = sacc;
        bij[i * OD + o] = sacc;
        lmax = fmaxf(lmax, sacc);
      } else {
        val[k] = -1e30f;
      }
    }
    red[tid] = lmax;
    __syncthreads();
    for (int st = 128; st > 0; st >>= 1) {
      if (tid < st) red[tid] = fmaxf(red[tid], red[tid + st]);
      __syncthreads();
    }
    const float gmax = red[0];
    __syncthreads();
    float lsum = 0.f;
#pragma unroll
    for (int k = 0; k < 5; ++k) {
      const int i = tid + k * 256;
      if (i < IC) lsum += __expf(val[k] - gmax);
    }
    red[tid] = lsum;
    __syncthreads();
    for (int st = 128; st > 0; st >>= 1) {
      if (tid < st) red[tid] += red[tid + st];
      __syncthreads();
    }
    if (tid == 0) {
      stats[2 * o] = gmax;
      stats[2 * o + 1] = 1.f / red[0];
    }
    __syncthreads();
  }
}

// ---------------- fused cooperative kernel ----------------------------------

__global__ __launch_bounds__(256) void fused_kernel(const float* __restrict__ x,
                                                    const float* __restrict__ W,
                                                    float* __restrict__ out,
                                                    float* __restrict__ s_part,
                                                    float* __restrict__ v,
                                                    float* __restrict__ bij,
                                                    float* __restrict__ stats,
                                                    float* __restrict__ u_part,
                                                    short* __restrict__ Bs) {
  __shared__ __align__(16) char smem[32768];  // union: xs 32KB / red 1KB
  float* xs = (float*)smem;
  float* red = (float*)smem;
  const int tid = threadIdx.x;
  const int wave = tid >> 6, lane = tid & 63;
  const int nblk = gridDim.x, blk = blockIdx.x;
  const int gtid = blk * 256 + tid, nthreads = nblk * 256;

  for (int iter = 0; iter < 3; ++iter) {
    phase_build_b(W, bij, stats, iter == 0, Bs, gtid, nthreads);
    gsync(nblk);
    for (int u = blk; u < SUNITS; u += nblk)
      phase_sgemm_unit(x, Bs, s_part, u, wave, lane);
    gsync(nblk);
    phase_squash(s_part, v, out, iter == 2, gtid, nthreads);
    if (iter == 2) break;
    gsync(nblk);
    phase_agree(x, W, v, u_part, xs, blk, nblk, tid);
    gsync(nblk);
    phase_route(u_part, bij, stats, iter > 0, red, blk, nblk, tid);
    gsync(nblk);
  }
}

// ---------------- standalone fallback kernels -------------------------------

__global__ __launch_bounds__(256) void build_b_kernel(const float* __restrict__ W,
                                                      const float* __restrict__ bij,
                                                      const float* __restrict__ stats,
                                                      int uniform, short* __restrict__ Bs) {
  phase_build_b(W, bij, stats, uniform, Bs, blockIdx.x * 256 + threadIdx.x, gridDim.x * 256);
}

__global__ __launch_bounds__(256) void sgemm_kernel(const float* __restrict__ x,
                                                    const short* __restrict__ Bs,
                                                    float* __restrict__ s_part) {
  for (int u = blockIdx.x; u < SUNITS; u += gridDim.x)
    phase_sgemm_unit(x, Bs, s_part, u, threadIdx.x >> 6, threadIdx.x & 63);
}

__global__ __launch_bounds__(256) void squash_kernel(const float* __restrict__ s_part,
                                                     float* __restrict__ v,
                                                     float* __restrict__ out,
                                                     int write_out) {
  phase_squash(s_part, v, out, write_out, blockIdx.x * 256 + threadIdx.x, gridDim.x * 256);
}

__global__ __launch_bounds__(256) void agree_kernel(const float* __restrict__ x,
                                                    const float* __restrict__ W,
                                                    const float* __restrict__ v,
                                                    float* __restrict__ u_part) {
  __shared__ __align__(16) float xs[128 * 64];
  phase_agree(x, W, v, u_part, xs, blockIdx.x, gridDim.x, threadIdx.x);
}

__global__ __launch_bounds__(256) void route_kernel(const float* __restrict__ u_part,
                                                    float* __restrict__ bij,
                                                    float* __restrict__ stats,
                                                    int add_prev) {
  __shared__ float red[256];
  phase_route(u_part, bij, stats, add_prev, red, blockIdx.x, gridDim.x, threadIdx.x);
}

// ---------------- launch ----------------------------------------------------

extern "C" void kernel_launch(void* const* d_in, const int* in_sizes, int n_in,
                              void* d_out, int out_size, void* d_ws, size_t ws_size,
                              hipStream_t stream) {
  const float* x = (const float*)d_in[0];  // [512,1152,8] fp32
  const float* W = (const float*)d_in[1];  // [1152,10,16,8] fp32
  float* out = (float*)d_out;              // [512,10,16] fp32

  // workspace ~15 MB of ~268 MB d_ws; all buffers written before read per call
  float* ws = (float*)d_ws;
  float* s_part = ws;                          // 36*81920 = 2,949,120 floats
  float* v = s_part + (size_t)NCS * SOP;       // 81920
  float* bij = v + SOP;                        // 11520
  float* stats = bij + IC * OD;                // 32
  float* u_part = stats + 32;                  // 16*11520 = 184,320
  short* Bs = (short*)(u_part + (size_t)NCB * IC * OD);  // 288*160*32 shorts

  // attempt coop unconditionally (R9 proved this captures+replays); fall back
  // to multi-launch only if the launch call itself errors.
  void* args[] = {(void*)&x, (void*)&W, (void*)&out, (void*)&s_part, (void*)&v,
                  (void*)&bij, (void*)&stats, (void*)&u_part, (void*)&Bs};
  hipError_t e = hipLaunchCooperativeKernel((const void*)fused_kernel, dim3(SUNITS), dim3(256),
                                            args, 0, stream);
  if (e != hipSuccess) {
    (void)hipGetLastError();  // clear
    for (int iter = 0; iter < 3; ++iter) {
      build_b_kernel<<<180, 256, 0, stream>>>(W, bij, stats, iter == 0, Bs);
      sgemm_kernel<<<SUNITS, 256, 0, stream>>>(x, Bs, s_part);
      squash_kernel<<<SOP / 256, 256, 0, stream>>>(s_part, v, out, iter == 2);
      if (iter < 2) {
        agree_kernel<<<SUNITS, 256, 0, stream>>>(x, W, v, u_part);
        route_kernel<<<OD, 256, 0, stream>>>(u_part, bij, stats, iter > 0);
      }
    }
  }
}

// Round 12
// 248.935 us; speedup vs baseline: 9.1989x; 9.1989x over previous
//
#include <hip/hip_runtime.h>
#include <hip/hip_bf16.h>

// DigitCaps dynamic routing. Output fp32.
// R12: minimized multi-launch (11 dispatches). Grid-wide sync is DEAD on this
// part: cg::sync=87us, custom tree=185us per sync (R9/R11 measured). Fuse
// route+build (u_part 737KB is L2-resident -> redundant per-block stats via
// shfl, block0 persists bij); sgemm full-N per block (x read once, NCS=72).
#define B 512
#define IC 1152
#define QD 8
#define OD 10
#define PD 16
#define KD (IC * QD)       // 9216
#define NKB (KD / 32)      // 288 K32 blocks
#define NCS 72             // K-chunks for s GEMM; 288/72 = 4 K-steps
#define KSTEPS (NKB / NCS)
#define NCB 16             // b-chunks for agreement
#define CSB (B / NCB)      // 32
#define SOP (B * OD * PD)  // 81920
#define IO (IC * OD)       // 11520

typedef short bf16x8 __attribute__((ext_vector_type(8)));
typedef float f32x4 __attribute__((ext_vector_type(4)));

__device__ __forceinline__ short f2bf(float f) {
  union { float f; unsigned u; } x;
  x.f = f;
  unsigned r = x.u + 0x7FFFu + ((x.u >> 16) & 1u);  // RNE to bf16
  return (short)(r >> 16);
}

// ---------------- routebuild: bij/softmax (redundant per block) + Bs build --
// mode 0: uniform c=1/IC (iter0, no routing inputs touched)
// mode 1: bij_new = sum_bc u_part      ; block0 writes bijA
// mode 2: bij_new = bijA + sum_bc u_part ; no bij write
// grid 180 x 256: one Bs item (kb,n) per thread (180*256 = 46080 = NKB*160).
__global__ __launch_bounds__(256) void routebuild_kernel(const float* __restrict__ W,
                                                         const float* __restrict__ u_part,
                                                         float* __restrict__ bijA,
                                                         short* __restrict__ Bs,
                                                         int mode) {
  __shared__ float bl[IO];        // bij_new, then exp(bij-mx) in-place
  __shared__ float wred[4][OD];   // per-wave partials
  __shared__ float mx[OD], inv[OD];
  const int tid = threadIdx.x;
  const int wave = tid >> 6, lane = tid & 63;

  if (mode != 0) {
    // ---- bij_new for all (i,o); thread t handles i = t, t+256, ... ----
    float lmax[OD];
#pragma unroll
    for (int o = 0; o < OD; ++o) lmax[o] = -1e30f;
    for (int i = tid; i < IC; i += 256) {
      float acc[OD];
      if (mode == 2) {
#pragma unroll
        for (int o = 0; o < OD; ++o) acc[o] = bijA[i * OD + o];
      } else {
#pragma unroll
        for (int o = 0; o < OD; ++o) acc[o] = 0.f;
      }
      for (int bc = 0; bc < NCB; ++bc) {
        const float* up = u_part + (size_t)bc * IO + i * OD;
        const float4 u0 = *(const float4*)up;
        const float4 u1 = *(const float4*)(up + 4);
        const float2 u2 = *(const float2*)(up + 8);
        acc[0] += u0.x; acc[1] += u0.y; acc[2] += u0.z; acc[3] += u0.w;
        acc[4] += u1.x; acc[5] += u1.y; acc[6] += u1.z; acc[7] += u1.w;
        acc[8] += u2.x; acc[9] += u2.y;
      }
#pragma unroll
      for (int o = 0; o < OD; ++o) {
        bl[i * OD + o] = acc[o];
        lmax[o] = fmaxf(lmax[o], acc[o]);
        if (mode == 1 && blockIdx.x == 0) bijA[i * OD + o] = acc[o];
      }
    }
    // ---- max per o: shfl within wave, then 4 partials in LDS ----
#pragma unroll
    for (int o = 0; o < OD; ++o) {
      float m = lmax[o];
#pragma unroll
      for (int s = 1; s < 64; s <<= 1) m = fmaxf(m, __shfl_xor(m, s));
      if (lane == 0) wred[wave][o] = m;
    }
    __syncthreads();
    if (tid < OD) {
      mx[tid] = fmaxf(fmaxf(wred[0][tid], wred[1][tid]),
                      fmaxf(wred[2][tid], wred[3][tid]));
    }
    __syncthreads();
    // ---- exp + sum per o ----
    float lsum[OD];
#pragma unroll
    for (int o = 0; o < OD; ++o) lsum[o] = 0.f;
    for (int i = tid; i < IC; i += 256) {
#pragma unroll
      for (int o = 0; o < OD; ++o) {
        const float e = __expf(bl[i * OD + o] - mx[o]);
        bl[i * OD + o] = e;
        lsum[o] += e;
      }
    }
    __syncthreads();  // all bl writes done before build reads
#pragma unroll
    for (int o = 0; o < OD; ++o) {
      float s = lsum[o];
#pragma unroll
      for (int st = 1; st < 64; st <<= 1) s += __shfl_xor(s, st);
      if (lane == 0) wred[wave][o] = s;
    }
    __syncthreads();
    if (tid < OD) {
      inv[tid] = 1.f / (wred[0][tid] + wred[1][tid] + wred[2][tid] + wred[3][tid]);
    }
    __syncthreads();
  }

  // ---- build one Bs item (kb,n) per thread ----
  const int t = blockIdx.x * 256 + tid;
  const int kb = t / 160, n = t % 160;
  const int o = n >> 4, p = n & 15;
  short ov[32];
#pragma unroll
  for (int quad = 0; quad < 4; ++quad) {
    const int i = kb * 4 + quad;
    const float ci = (mode == 0) ? (1.0f / (float)IC) : (bl[i * OD + o] * inv[o]);
    const float4* wp = (const float4*)(W + (((size_t)i * OD + o) * PD + p) * QD);
    const float4 w0 = wp[0], w1 = wp[1];
    ov[quad * 8 + 0] = f2bf(ci * w0.x); ov[quad * 8 + 1] = f2bf(ci * w0.y);
    ov[quad * 8 + 2] = f2bf(ci * w0.z); ov[quad * 8 + 3] = f2bf(ci * w0.w);
    ov[quad * 8 + 4] = f2bf(ci * w1.x); ov[quad * 8 + 5] = f2bf(ci * w1.y);
    ov[quad * 8 + 6] = f2bf(ci * w1.z); ov[quad * 8 + 7] = f2bf(ci * w1.w);
  }
  int4* dst = (int4*)(Bs + (size_t)t * 32);
  const int4* src = (const int4*)ov;
#pragma unroll
  for (int j = 0; j < 4; ++j) dst[j] = src[j];
}

// ---------------- sgemm: s_part[cz][b][n], full 160-N per block -------------
// block = cz + NCS*mb; 4 waves = 4 m-subtiles of 16 rows; acc f32x4[10].
__global__ __launch_bounds__(256) void sgemm_kernel(const float* __restrict__ x,
                                                    const short* __restrict__ Bs,
                                                    float* __restrict__ s_part) {
  const int tid = threadIdx.x;
  const int wave = tid >> 6, lane = tid & 63;
  const int ln = lane & 15, quad = lane >> 4;
  const int cz = blockIdx.x % NCS, mb = blockIdx.x / NCS;
  const int m0 = mb * 64 + wave * 16;
  f32x4 acc[10] = {};
  const float* arow = x + (size_t)(m0 + ln) * KD + quad * 8;
#pragma unroll
  for (int step = 0; step < KSTEPS; ++step) {
    const int kb = cz * KSTEPS + step;
    const float* ap = arow + kb * 32;
    const f32x4 a0 = *(const f32x4*)ap;
    const f32x4 a1 = *(const f32x4*)(ap + 4);
    bf16x8 af;
    af[0] = f2bf(a0[0]); af[1] = f2bf(a0[1]); af[2] = f2bf(a0[2]); af[3] = f2bf(a0[3]);
    af[4] = f2bf(a1[0]); af[5] = f2bf(a1[1]); af[6] = f2bf(a1[2]); af[7] = f2bf(a1[3]);
    const short* bp = Bs + (size_t)kb * 5120 + ln * 32 + quad * 8;
#pragma unroll
    for (int nt = 0; nt < 10; ++nt) {
      const bf16x8 bf = *(const bf16x8*)(bp + nt * 512);  // 16 n-rows * 32
      acc[nt] = __builtin_amdgcn_mfma_f32_16x16x32_bf16(af, bf, acc[nt], 0, 0, 0);
    }
  }
  // C/D layout: col = lane&15, row = quad*4 + reg  [m89-verified]
  float* sp = s_part + (size_t)cz * SOP;
#pragma unroll
  for (int nt = 0; nt < 10; ++nt)
#pragma unroll
    for (int r = 0; r < 4; ++r)
      sp[(size_t)(m0 + quad * 4 + r) * 160 + nt * 16 + ln] = acc[nt][r];
}

// ---------------- squash: reduce NCS partials + squash ----------------------
__global__ __launch_bounds__(256) void squash_kernel(const float* __restrict__ s_part,
                                                     float* __restrict__ v,
                                                     float* __restrict__ out,
                                                     int write_out) {
  const int t = blockIdx.x * 256 + threadIdx.x;  // < 81920
  float sv = 0.f;
#pragma unroll 8
  for (int ch = 0; ch < NCS; ++ch) sv += s_part[(size_t)ch * SOP + t];
  float sq = sv * sv;
#pragma unroll
  for (int m = 1; m < 16; m <<= 1) sq += __shfl_xor(sq, m, 16);
  const float norm = sqrtf(sq + 1e-8f);
  const float val = sv * (sq / ((1.f + sq) * norm));
  v[t] = val;
  if (write_out) out[t] = val;
}

// ---------------- agree: u_part[bc][i][o], x staged in LDS ------------------
// block = ig*4 + bquad (576); stage x[bq*128..+128)[ig*8..+8)[:] (32KB);
// 4 waves = 4 b-chunks of 32; 5 o-pairs reuse tile.
__global__ __launch_bounds__(256) void agree_kernel(const float* __restrict__ x,
                                                    const float* __restrict__ W,
                                                    const float* __restrict__ v,
                                                    float* __restrict__ u_part) {
  __shared__ __align__(16) float xs[128 * 64];
  const int tid = threadIdx.x;
  const int wave = tid >> 6, lane = tid & 63;
  const int il = lane >> 3, q = lane & 7;
  const int ig = blockIdx.x >> 2, bquad = blockIdx.x & 3;
  const int bbase = bquad * 128;
  const int i = ig * 8 + il;
  for (int idx = tid; idx < 2048; idx += 256) {
    const int row = idx >> 4, f4 = idx & 15;
    *(float4*)(xs + row * 64 + f4 * 4) =
        *(const float4*)(x + (size_t)(bbase + row) * KD + ig * 64 + f4 * 4);
  }
  __syncthreads();
  const int bc = bquad * 4 + wave;
  const int b0 = bc * CSB;
  const float* xw = xs + wave * 32 * 64 + il * 8 + q;
#pragma unroll
  for (int opair = 0; opair < 5; ++opair) {
    const int o1 = opair, o2 = opair + 5;
    float G0[PD], G1[PD];
#pragma unroll
    for (int p = 0; p < PD; ++p) { G0[p] = 0.f; G1[p] = 0.f; }
    for (int b = 0; b < CSB; ++b) {
      const float xa = xw[b * 64];
      const int vo0 = __builtin_amdgcn_readfirstlane(((b0 + b) * OD + o1) * PD);
      const int vo1 = __builtin_amdgcn_readfirstlane(((b0 + b) * OD + o2) * PD);
      const float4* vp0 = (const float4*)(v + vo0);
      const float4* vp1 = (const float4*)(v + vo1);
      const float4 a0 = vp0[0], a1 = vp0[1], a2 = vp0[2], a3 = vp0[3];
      const float4 c0 = vp1[0], c1 = vp1[1], c2 = vp1[2], c3 = vp1[3];
      const float va[PD] = {a0.x, a0.y, a0.z, a0.w, a1.x, a1.y, a1.z, a1.w,
                            a2.x, a2.y, a2.z, a2.w, a3.x, a3.y, a3.z, a3.w};
      const float vc[PD] = {c0.x, c0.y, c0.z, c0.w, c1.x, c1.y, c1.z, c1.w,
                            c2.x, c2.y, c2.z, c2.w, c3.x, c3.y, c3.z, c3.w};
#pragma unroll
      for (int p = 0; p < PD; ++p) G0[p] = fmaf(xa, va[p], G0[p]);
#pragma unroll
      for (int p = 0; p < PD; ++p) G1[p] = fmaf(xa, vc[p], G1[p]);
    }
    const float* wq1 = W + ((size_t)(i * OD + o1) * PD) * QD + q;
    const float* wq2 = W + ((size_t)(i * OD + o2) * PD) * QD + q;
    float u0s = 0.f, u1s = 0.f;
#pragma unroll
    for (int p = 0; p < PD; ++p) {
      u0s = fmaf(wq1[(size_t)p * QD], G0[p], u0s);
      u1s = fmaf(wq2[(size_t)p * QD], G1[p], u1s);
    }
    u0s += __shfl_xor(u0s, 1); u0s += __shfl_xor(u0s, 2); u0s += __shfl_xor(u0s, 4);
    u1s += __shfl_xor(u1s, 1); u1s += __shfl_xor(u1s, 2); u1s += __shfl_xor(u1s, 4);
    if (q == 0) {
      float* up = u_part + ((size_t)bc * IC + i) * OD;
      up[o1] = u0s * (1.0f / (float)B);
      up[o2] = u1s * (1.0f / (float)B);
    }
  }
}

// ---------------- launch: 11 dispatches --------------------------------------

extern "C" void kernel_launch(void* const* d_in, const int* in_sizes, int n_in,
                              void* d_out, int out_size, void* d_ws, size_t ws_size,
                              hipStream_t stream) {
  const float* x = (const float*)d_in[0];  // [512,1152,8] fp32
  const float* W = (const float*)d_in[1];  // [1152,10,16,8] fp32
  float* out = (float*)d_out;              // [512,10,16] fp32

  // workspace ~27.5 MB of ~268 MB; every buffer written before read per call
  float* ws = (float*)d_ws;
  float* s_part = ws;                          // 72*81920 = 5,898,240 floats
  float* v = s_part + (size_t)NCS * SOP;       // 81920
  float* bijA = v + SOP;                       // 11520
  float* u_part = bijA + IO;                   // 16*11520 = 184,320
  short* Bs = (short*)(u_part + (size_t)NCB * IO);  // 288*160*32 shorts

  // iter 1
  routebuild_kernel<<<180, 256, 0, stream>>>(W, u_part, bijA, Bs, 0);
  sgemm_kernel<<<8 * NCS, 256, 0, stream>>>(x, Bs, s_part);
  squash_kernel<<<SOP / 256, 256, 0, stream>>>(s_part, v, out, 0);
  agree_kernel<<<576, 256, 0, stream>>>(x, W, v, u_part);
  // iter 2
  routebuild_kernel<<<180, 256, 0, stream>>>(W, u_part, bijA, Bs, 1);
  sgemm_kernel<<<8 * NCS, 256, 0, stream>>>(x, Bs, s_part);
  squash_kernel<<<SOP / 256, 256, 0, stream>>>(s_part, v, out, 0);
  agree_kernel<<<576, 256, 0, stream>>>(x, W, v, u_part);
  // iter 3
  routebuild_kernel<<<180, 256, 0, stream>>>(W, u_part, bijA, Bs, 2);
  sgemm_kernel<<<8 * NCS, 256, 0, stream>>>(x, Bs, s_part);
  squash_kernel<<<SOP / 256, 256, 0, stream>>>(s_part, v, out, 1);
}

// Round 13
// 184.386 us; speedup vs baseline: 12.4192x; 1.3501x over previous
//
#include <hip/hip_runtime.h>
#include <hip/hip_bf16.h>

// DigitCaps dynamic routing. Output fp32.
// R13: agreement moved to MFMA (G[(i,q),(o,p)] = sum_b x*v as bf16 GEMM,
// M=9216 N=160 K=512 split 4x) — R12 measured VALU-agree at 43us x2 with a
// structural >=25us floor. vB uses R7's verified B-frag swizzle (emitted by
// squash); A-frags packed in LDS (m120-verified layout). routebuild NCB=4.
#define B 512
#define IC 1152
#define QD 8
#define OD 10
#define PD 16
#define KD (IC * QD)       // 9216
#define NKB (KD / 32)      // 288 K32 blocks
#define NCS 72             // K-chunks for s GEMM; 288/72 = 4 K-steps
#define KSTEPS (NKB / NCS)
#define NCB 4              // K-chunks for agreement GEMM (b-dim, 128 each)
#define SOP (B * OD * PD)  // 81920
#define IO (IC * OD)       // 11520

typedef short bf16x8 __attribute__((ext_vector_type(8)));
typedef float f32x4 __attribute__((ext_vector_type(4)));

__device__ __forceinline__ short f2bf(float f) {
  union { float f; unsigned u; } x;
  x.f = f;
  unsigned r = x.u + 0x7FFFu + ((x.u >> 16) & 1u);  // RNE to bf16
  return (short)(r >> 16);
}

// ---------------- routebuild: bij/softmax (redundant per block) + Bs build --
// mode 0: uniform c=1/IC; mode 1: bij=sum(u_part), block0 persists; mode 2: +=bijA.
__global__ __launch_bounds__(256) void routebuild_kernel(const float* __restrict__ W,
                                                         const float* __restrict__ u_part,
                                                         float* __restrict__ bijA,
                                                         short* __restrict__ Bs,
                                                         int mode) {
  __shared__ float bl[IO];
  __shared__ float wred[4][OD];
  __shared__ float mx[OD], inv[OD];
  const int tid = threadIdx.x;
  const int wave = tid >> 6, lane = tid & 63;

  if (mode != 0) {
    float lmax[OD];
#pragma unroll
    for (int o = 0; o < OD; ++o) lmax[o] = -1e30f;
    for (int i = tid; i < IC; i += 256) {
      float acc[OD];
      if (mode == 2) {
#pragma unroll
        for (int o = 0; o < OD; ++o) acc[o] = bijA[i * OD + o];
      } else {
#pragma unroll
        for (int o = 0; o < OD; ++o) acc[o] = 0.f;
      }
      for (int bc = 0; bc < NCB; ++bc) {
        const float* up = u_part + (size_t)bc * IO + i * OD;
        const float4 u0 = *(const float4*)up;
        const float4 u1 = *(const float4*)(up + 4);
        const float2 u2 = *(const float2*)(up + 8);
        acc[0] += u0.x; acc[1] += u0.y; acc[2] += u0.z; acc[3] += u0.w;
        acc[4] += u1.x; acc[5] += u1.y; acc[6] += u1.z; acc[7] += u1.w;
        acc[8] += u2.x; acc[9] += u2.y;
      }
#pragma unroll
      for (int o = 0; o < OD; ++o) {
        bl[i * OD + o] = acc[o];
        lmax[o] = fmaxf(lmax[o], acc[o]);
        if (mode == 1 && blockIdx.x == 0) bijA[i * OD + o] = acc[o];
      }
    }
#pragma unroll
    for (int o = 0; o < OD; ++o) {
      float m = lmax[o];
#pragma unroll
      for (int s = 1; s < 64; s <<= 1) m = fmaxf(m, __shfl_xor(m, s));
      if (lane == 0) wred[wave][o] = m;
    }
    __syncthreads();
    if (tid < OD)
      mx[tid] = fmaxf(fmaxf(wred[0][tid], wred[1][tid]),
                      fmaxf(wred[2][tid], wred[3][tid]));
    __syncthreads();
    float lsum[OD];
#pragma unroll
    for (int o = 0; o < OD; ++o) lsum[o] = 0.f;
    for (int i = tid; i < IC; i += 256) {
#pragma unroll
      for (int o = 0; o < OD; ++o) {
        const float e = __expf(bl[i * OD + o] - mx[o]);
        bl[i * OD + o] = e;
        lsum[o] += e;
      }
    }
    __syncthreads();
#pragma unroll
    for (int o = 0; o < OD; ++o) {
      float s = lsum[o];
#pragma unroll
      for (int st = 1; st < 64; st <<= 1) s += __shfl_xor(s, st);
      if (lane == 0) wred[wave][o] = s;
    }
    __syncthreads();
    if (tid < OD)
      inv[tid] = 1.f / (wred[0][tid] + wred[1][tid] + wred[2][tid] + wred[3][tid]);
    __syncthreads();
  }

  const int t = blockIdx.x * 256 + tid;
  const int kb = t / 160, n = t % 160;
  const int o = n >> 4, p = n & 15;
  short ov[32];
#pragma unroll
  for (int quad = 0; quad < 4; ++quad) {
    const int i = kb * 4 + quad;
    const float ci = (mode == 0) ? (1.0f / (float)IC) : (bl[i * OD + o] * inv[o]);
    const float4* wp = (const float4*)(W + (((size_t)i * OD + o) * PD + p) * QD);
    const float4 w0 = wp[0], w1 = wp[1];
    ov[quad * 8 + 0] = f2bf(ci * w0.x); ov[quad * 8 + 1] = f2bf(ci * w0.y);
    ov[quad * 8 + 2] = f2bf(ci * w0.z); ov[quad * 8 + 3] = f2bf(ci * w0.w);
    ov[quad * 8 + 4] = f2bf(ci * w1.x); ov[quad * 8 + 5] = f2bf(ci * w1.y);
    ov[quad * 8 + 6] = f2bf(ci * w1.z); ov[quad * 8 + 7] = f2bf(ci * w1.w);
  }
  int4* dst = (int4*)(Bs + (size_t)t * 32);
  const int4* src = (const int4*)ov;
#pragma unroll
  for (int j = 0; j < 4; ++j) dst[j] = src[j];
}

// ---------------- sgemm: s_part[cz][b][n], full 160-N per block (R12 form) --
__global__ __launch_bounds__(256) void sgemm_kernel(const float* __restrict__ x,
                                                    const short* __restrict__ Bs,
                                                    float* __restrict__ s_part) {
  const int tid = threadIdx.x;
  const int wave = tid >> 6, lane = tid & 63;
  const int ln = lane & 15, quad = lane >> 4;
  const int cz = blockIdx.x % NCS, mb = blockIdx.x / NCS;
  const int m0 = mb * 64 + wave * 16;
  f32x4 acc[10] = {};
  const float* arow = x + (size_t)(m0 + ln) * KD + quad * 8;
#pragma unroll
  for (int step = 0; step < KSTEPS; ++step) {
    const int kb = cz * KSTEPS + step;
    const float* ap = arow + kb * 32;
    const f32x4 a0 = *(const f32x4*)ap;
    const f32x4 a1 = *(const f32x4*)(ap + 4);
    bf16x8 af;
    af[0] = f2bf(a0[0]); af[1] = f2bf(a0[1]); af[2] = f2bf(a0[2]); af[3] = f2bf(a0[3]);
    af[4] = f2bf(a1[0]); af[5] = f2bf(a1[1]); af[6] = f2bf(a1[2]); af[7] = f2bf(a1[3]);
    const short* bp = Bs + (size_t)kb * 5120 + ln * 32 + quad * 8;
#pragma unroll
    for (int nt = 0; nt < 10; ++nt) {
      const bf16x8 bf = *(const bf16x8*)(bp + nt * 512);
      acc[nt] = __builtin_amdgcn_mfma_f32_16x16x32_bf16(af, bf, acc[nt], 0, 0, 0);
    }
  }
  float* sp = s_part + (size_t)cz * SOP;
#pragma unroll
  for (int nt = 0; nt < 10; ++nt)
#pragma unroll
    for (int r = 0; r < 4; ++r)
      sp[(size_t)(m0 + quad * 4 + r) * 160 + nt * 16 + ln] = acc[nt][r];
}

// ---------------- squash: reduce + squash; emit vB (B-frag bf16) or out -----
// vB[kb][n][b&31] = bf16(v[b][n]), kb=b>>5 — same verified swizzle as Bs.
__global__ __launch_bounds__(256) void squash_kernel(const float* __restrict__ s_part,
                                                     short* __restrict__ vB,
                                                     float* __restrict__ out,
                                                     int write_out) {
  const int t = blockIdx.x * 256 + threadIdx.x;  // < 81920, t = b*160 + n
  float sv = 0.f;
#pragma unroll 8
  for (int ch = 0; ch < NCS; ++ch) sv += s_part[(size_t)ch * SOP + t];
  float sq = sv * sv;
#pragma unroll
  for (int m = 1; m < 16; m <<= 1) sq += __shfl_xor(sq, m, 16);
  const float norm = sqrtf(sq + 1e-8f);
  const float val = sv * (sq / ((1.f + sq) * norm));
  if (write_out) {
    out[t] = val;
  } else {
    const int b = t / 160, n = t - b * 160;
    vB[((size_t)(b >> 5) * 160 + n) * 32 + (b & 31)] = f2bf(val);
  }
}

// ---------------- aggemm: u_part[kq][i][o] via MFMA -------------------------
// G[m=(i8q),(n=o*16+p)] = sum_b x[b,iq]*v[b,op]; block = (ig8, kq): 8 i x 128 b.
// 4 waves = 4 m-tiles of 16 iq. Epilogue contracts with W in-register.
__global__ __launch_bounds__(256) void aggemm_kernel(const float* __restrict__ x,
                                                     const float* __restrict__ W,
                                                     const short* __restrict__ vB,
                                                     float* __restrict__ u_part) {
  __shared__ __align__(16) short Abuf[16 * 64 * 8];  // [mt*4+kb][lane][8] bf16, 16KB
  const int tid = threadIdx.x;
  const int ig8 = blockIdx.x, kq = blockIdx.y;
  const int b0 = kq * 128;
  // stage x -> A-frag layout: A[m=lane&15][k=quad*8+j]  [m120-verified]
#pragma unroll
  for (int j = 0; j < 8; ++j) {
    const int idx = tid + j * 256;       // 0..2047
    const int b = idx >> 4, f4 = idx & 15;
    const float4 vx = *(const float4*)(x + (size_t)(b0 + b) * KD + ig8 * 64 + f4 * 4);
    const int kb = b >> 5, qk = (b & 31) >> 3, jj = b & 7;
    const int mt = (f4 * 4) >> 4;        // same for all 4 elements
    const int mlb = (f4 & 3) * 4;
    short* dst = Abuf + (((mt * 4 + kb) * 64 + qk * 16 + mlb) * 8 + jj);
    dst[0] = f2bf(vx.x); dst[8] = f2bf(vx.y); dst[16] = f2bf(vx.z); dst[24] = f2bf(vx.w);
  }
  __syncthreads();
  const int mt = tid >> 6, lane = tid & 63;
  const int ln = lane & 15, quad = lane >> 4;
  f32x4 acc[10] = {};
#pragma unroll
  for (int kb = 0; kb < 4; ++kb) {
    const bf16x8 af = *(const bf16x8*)(Abuf + ((mt * 4 + kb) * 64 + lane) * 8);
    const short* bp = vB + ((size_t)(kq * 4 + kb) * 160 + ln) * 32 + quad * 8;
#pragma unroll
    for (int nt = 0; nt < 10; ++nt) {
      const bf16x8 bf = *(const bf16x8*)(bp + nt * 512);
      acc[nt] = __builtin_amdgcn_mfma_f32_16x16x32_bf16(af, bf, acc[nt], 0, 0, 0);
    }
  }
  // epilogue: lane holds G[m=quad*4+r][p=ln] for o=nt.
  // m = i_loc*8+q -> i_loc = quad>>1, q = (quad&1)*4 + r (r consecutive).
  const int i = ig8 * 8 + mt * 2 + (quad >> 1);
  const int qb = (quad & 1) * 4;
#pragma unroll
  for (int nt = 0; nt < 10; ++nt) {
    const float4 wv = *(const float4*)(W + (((size_t)i * OD + nt) * PD + ln) * QD + qb);
    float pa = acc[nt][0] * wv.x + acc[nt][1] * wv.y + acc[nt][2] * wv.z + acc[nt][3] * wv.w;
    pa += __shfl_xor(pa, 1); pa += __shfl_xor(pa, 2); pa += __shfl_xor(pa, 4);
    pa += __shfl_xor(pa, 8); pa += __shfl_xor(pa, 16);
    if ((lane & 31) == 0)
      u_part[(size_t)kq * IO + i * OD + nt] = pa * (1.0f / (float)B);
  }
}

// ---------------- launch: 11 dispatches --------------------------------------

extern "C" void kernel_launch(void* const* d_in, const int* in_sizes, int n_in,
                              void* d_out, int out_size, void* d_ws, size_t ws_size,
                              hipStream_t stream) {
  const float* x = (const float*)d_in[0];  // [512,1152,8] fp32
  const float* W = (const float*)d_in[1];  // [1152,10,16,8] fp32
  float* out = (float*)d_out;              // [512,10,16] fp32

  // workspace ~29.5 MB of ~268 MB; every buffer written before read per call
  float* ws = (float*)d_ws;
  float* s_part = ws;                               // 72*81920
  float* bijA = s_part + (size_t)NCS * SOP;         // 11520
  float* u_part = bijA + IO;                        // 4*11520
  short* vB = (short*)(u_part + (size_t)NCB * IO);  // 16*160*32 = 81920 shorts
  short* Bs = vB + (size_t)16 * 160 * 32;           // 288*160*32 shorts

  const dim3 agrid(144, NCB);

  // iter 1
  routebuild_kernel<<<180, 256, 0, stream>>>(W, u_part, bijA, Bs, 0);
  sgemm_kernel<<<8 * NCS, 256, 0, stream>>>(x, Bs, s_part);
  squash_kernel<<<SOP / 256, 256, 0, stream>>>(s_part, vB, out, 0);
  aggemm_kernel<<<agrid, 256, 0, stream>>>(x, W, vB, u_part);
  // iter 2
  routebuild_kernel<<<180, 256, 0, stream>>>(W, u_part, bijA, Bs, 1);
  sgemm_kernel<<<8 * NCS, 256, 0, stream>>>(x, Bs, s_part);
  squash_kernel<<<SOP / 256, 256, 0, stream>>>(s_part, vB, out, 0);
  aggemm_kernel<<<agrid, 256, 0, stream>>>(x, W, vB, u_part);
  // iter 3
  routebuild_kernel<<<180, 256, 0, stream>>>(W, u_part, bijA, Bs, 2);
  sgemm_kernel<<<8 * NCS, 256, 0, stream>>>(x, Bs, s_part);
  squash_kernel<<<SOP / 256, 256, 0, stream>>>(s_part, vB, out, 1);
}